// Round 12
// baseline (45.302 us; speedup 1.0000x reference)
//
#include <hip/hip_runtime.h>

constexpr int NPIX  = 1 << 20;      // 1024*1024 pixels
constexpr int NCLS  = 21;
constexpr int NBINS = 480;          // linear bins over [0,8): width = 1/60
constexpr float RANGE = 8.0f;
constexpr float BIN_SCALE = NBINS / RANGE;   // 60
constexpr int NCHUNK = 256;
constexpr int CHUNK_PIX = NPIX / NCHUNK;     // 4096 pixels = 1024 quads
constexpr int NGRP = 8;                      // merge hierarchy
constexpr int CPG  = NCHUNK / NGRP;          // 32 chunks per group

typedef int   iv4 __attribute__((ext_vector_type(4)));
typedef float fv4 __attribute__((ext_vector_type(4)));

// ---------------------------------------------------------------------------
// 1) FUSED argmax + 21-class LDS histograms (R9 structure). ONE change vs R9:
//    pred loads are STAGED FIRST (not needed until after argmax -> their
//    latency hides under the label stream + argmax compute), keeping the
//    memory pipe full across both phases. Grid 256 = 1 block/CU; 16 waves.
// ---------------------------------------------------------------------------
__global__ void __launch_bounds__(1024, 4)
k_fused(const iv4* __restrict__ label4, const fv4* __restrict__ pred4,
        unsigned int* __restrict__ part) {
    __shared__ unsigned int sh[NCLS * NBINS];          // 39.375 KB
    const int chunk = blockIdx.x;
    const int t     = threadIdx.x;

    {   // zero LDS (vectorized)
        uint4* s4 = (uint4*)sh;
        for (int b = t; b < NCLS * NBINS / 4; b += 1024)
            s4[b] = make_uint4(0u, 0u, 0u, 0u);
    }

    const int q = chunk * (CHUNK_PIX / 4) + t;         // this thread's quad

    // ---- stage all 21 PRED loads FIRST (latency hidden under argmax phase)
    fv4 pv[NCLS];
    #pragma unroll
    for (int c = 0; c < NCLS; ++c)
        pv[c] = pred4[(size_t)c * (NPIX / 4) + q];

    // ---- stage all 21 label loads (independent, all in flight)
    iv4 lv[NCLS];
    #pragma unroll
    for (int c = 0; c < NCLS; ++c)
        lv[c] = label4[(size_t)c * (NPIX / 4) + q];

    // ---- register-only argmax (strict > keeps FIRST max, like jnp.argmax)
    int bx = 0, by = 0, bz = 0, bw = 0;
    iv4 best = lv[0];
    #pragma unroll
    for (int c = 1; c < NCLS; ++c) {
        if (lv[c].x > best.x) { best.x = lv[c].x; bx = c; }
        if (lv[c].y > best.y) { best.y = lv[c].y; by = c; }
        if (lv[c].z > best.z) { best.z = lv[c].z; bz = c; }
        if (lv[c].w > best.w) { best.w = lv[c].w; bw = c; }
    }

    __syncthreads();                                   // LDS zero visible

    // ---- histogram: u32 bin packs (n | n_fg<<16); chunk=4096 px fits u16
    #pragma unroll
    for (int c = 0; c < NCLS; ++c) {
        unsigned int* shc = sh + c * NBINS;
        {
            unsigned int fg = (bx == c) ? 1u : 0u;
            float e = fabsf((float)fg - pv[c].x);
            int bin = (int)(e * BIN_SCALE); bin = bin < NBINS - 1 ? bin : NBINS - 1;
            atomicAdd(&shc[bin], 1u | (fg << 16));
        }
        {
            unsigned int fg = (by == c) ? 1u : 0u;
            float e = fabsf((float)fg - pv[c].y);
            int bin = (int)(e * BIN_SCALE); bin = bin < NBINS - 1 ? bin : NBINS - 1;
            atomicAdd(&shc[bin], 1u | (fg << 16));
        }
        {
            unsigned int fg = (bz == c) ? 1u : 0u;
            float e = fabsf((float)fg - pv[c].z);
            int bin = (int)(e * BIN_SCALE); bin = bin < NBINS - 1 ? bin : NBINS - 1;
            atomicAdd(&shc[bin], 1u | (fg << 16));
        }
        {
            unsigned int fg = (bw == c) ? 1u : 0u;
            float e = fabsf((float)fg - pv[c].w);
            int bin = (int)(e * BIN_SCALE); bin = bin < NBINS - 1 ? bin : NBINS - 1;
            atomicAdd(&shc[bin], 1u | (fg << 16));
        }
    }
    __syncthreads();

    // ---- flush: block-contiguous, coalesced 16B stores
    uint4* dst = (uint4*)(part + (size_t)chunk * NCLS * NBINS);
    const uint4* src = (const uint4*)sh;
    for (int b = t; b < NCLS * NBINS / 4; b += 1024) dst[b] = src[b];
}

// ---------------------------------------------------------------------------
// 2) hierarchical merge: each (bin-block, group) sums 32 chunks -> u64 part2.
//    Block (0,0) thread 0 also zeroes out[0] for k_scanfinal's atomics.
// ---------------------------------------------------------------------------
__global__ void k_merge(const unsigned int* __restrict__ part,
                        unsigned long long* __restrict__ part2,
                        float* __restrict__ out) {
    if (blockIdx.x == 0 && blockIdx.y == 0 && threadIdx.x == 0) out[0] = 0.0f;
    int b = blockIdx.x * blockDim.x + threadIdx.x;     // over NCLS*NBINS
    if (b >= NCLS * NBINS) return;
    int g = blockIdx.y;
    unsigned int n = 0, f = 0;
    #pragma unroll 8
    for (int k = 0; k < CPG; ++k) {
        unsigned int v = part[(size_t)(g * CPG + k) * (NCLS * NBINS) + b];
        n += v & 0xFFFFu;
        f += v >> 16;
    }
    part2[(size_t)g * (NCLS * NBINS) + b] =
        (unsigned long long)n | ((unsigned long long)f << 32);
}

// ---------------------------------------------------------------------------
// 3) per-class descending scan + Lovasz dot + mean, fused: each class block
//    atomically adds loss_c/NCLS into out[0] (zeroed by k_merge).
// ---------------------------------------------------------------------------
__global__ void __launch_bounds__(512)
k_scanfinal(const unsigned long long* __restrict__ part2, float* __restrict__ out) {
    const int c    = blockIdx.x;
    const int t    = threadIdx.x;
    const int lane = t & 63;
    const int wv   = t >> 6;                           // 8 waves

    // rank t: 0 = largest-error bin. Threads >= NBINS are zero-padding.
    const int bin = NBINS - 1 - t;
    unsigned int tn = 0, tf = 0;
    if (t < NBINS) {
        #pragma unroll
        for (int g = 0; g < NGRP; ++g) {
            unsigned long long v =
                part2[(size_t)g * (NCLS * NBINS) + (size_t)c * NBINS + bin];
            tn += (unsigned int)v;
            tf += (unsigned int)(v >> 32);
        }
    }

    // wave-inclusive scan of (tn, tf)
    unsigned int in_ = tn, if_ = tf;
    #pragma unroll
    for (int off = 1; off < 64; off <<= 1) {
        unsigned int an = __shfl_up(in_, off, 64);
        unsigned int af = __shfl_up(if_, off, 64);
        if (lane >= off) { in_ += an; if_ += af; }
    }

    __shared__ unsigned int swn[8], swf[8];
    if (lane == 63) { swn[wv] = in_; swf[wv] = if_; }
    __syncthreads();

    if (wv == 0 && lane < 8) {                         // scan the 8 wave totals
        unsigned int a = swn[lane], b = swf[lane];
        #pragma unroll
        for (int off = 1; off < 8; off <<= 1) {
            unsigned int an = __shfl_up(a, off, 64);
            unsigned int af = __shfl_up(b, off, 64);
            if (lane >= off) { a += an; b += af; }
        }
        swn[lane] = a; swf[lane] = b;                  // inclusive wave prefixes
    }
    __syncthreads();

    const unsigned int G = swf[7];                     // total foreground count
    unsigned int i = in_ - tn + (wv ? swn[wv - 1] : 0u);   // exclusive prefix
    unsigned int F = if_ - tf + (wv ? swf[wv - 1] : 0u);

    double acc = 0.0;
    if (tn) {
        double jprev = (i > 0) ? (double)i / (double)(G + i - F) : 0.0;
        unsigned int i2 = i + tn, F2 = F + tf;
        double jhi = (double)i2 / (double)(G + i2 - F2);
        acc = ((bin + 0.5) * (double)(RANGE / NBINS)) * (jhi - jprev);
    }

    // block reduce, then one atomicAdd per class
    #pragma unroll
    for (int off = 32; off > 0; off >>= 1) acc += __shfl_down(acc, off, 64);
    __shared__ double sd[8];
    if (lane == 0) sd[wv] = acc;
    __syncthreads();
    if (t == 0) {
        double s = 0.0;
        #pragma unroll
        for (int k = 0; k < 8; ++k) s += sd[k];
        atomicAdd(out, (float)(s / NCLS));
    }
}

extern "C" void kernel_launch(void* const* d_in, const int* in_sizes, int n_in,
                              void* d_out, int out_size, void* d_ws, size_t ws_size,
                              hipStream_t stream) {
    const float* pred  = (const float*)d_in[0];
    const int*   label = (const int*)d_in[1];
    float* out = (float*)d_out;

    char* ws = (char*)d_ws;
    unsigned int* part = (unsigned int*)ws;                      // 10.3 MB
    size_t off = (size_t)NCHUNK * NCLS * NBINS * 4;
    unsigned long long* part2 = (unsigned long long*)(ws + off); // 645 KB

    k_fused<<<NCHUNK, 1024, 0, stream>>>((const iv4*)label, (const fv4*)pred, part);
    dim3 mgrid((NCLS * NBINS + 255) / 256, NGRP);
    k_merge<<<mgrid, 256, 0, stream>>>(part, part2, out);
    k_scanfinal<<<NCLS, 512, 0, stream>>>(part2, out);
}

// Round 13
// 39.419 us; speedup vs baseline: 1.1492x; 1.1492x over previous
//
#include <hip/hip_runtime.h>

constexpr int NPIX  = 1 << 20;      // 1024*1024 pixels
constexpr int NCLS  = 21;
constexpr int NBINS = 480;          // linear bins over [0,8): width = 1/60
constexpr float RANGE = 8.0f;
constexpr float BIN_SCALE = NBINS / RANGE;   // 60
constexpr int NCHUNK = 32;
constexpr int CHUNK_PIX = NPIX / NCHUNK;     // 32768 (fits u16 bin counts)

typedef int   iv4 __attribute__((ext_vector_type(4)));
typedef float fv4 __attribute__((ext_vector_type(4)));

// ---------------------------------------------------------------------------
// 1) per-pixel argmax (single-phase label stream, ~6 TB/s proven in R3).
//    int4 loads, uchar4 result (1 MB -> L2-resident for k_hist's re-reads).
//    Block 0 also zeroes the global hist (80.6 KB) and out[0].
// ---------------------------------------------------------------------------
__global__ void k_argmax(const iv4* __restrict__ label4, uchar4* __restrict__ lbl,
                         unsigned long long* __restrict__ hist,
                         float* __restrict__ out) {
    int i = blockIdx.x * blockDim.x + threadIdx.x;     // over NPIX/4
    if (blockIdx.x == 0) {
        for (int b = threadIdx.x; b < NCLS * NBINS; b += blockDim.x)
            hist[b] = 0ULL;
        if (threadIdx.x == 0) out[0] = 0.0f;
    }
    if (i >= NPIX / 4) return;
    iv4 best = label4[i];
    int bx = 0, by = 0, bz = 0, bw = 0;
    #pragma unroll
    for (int c = 1; c < NCLS; ++c) {
        iv4 v = label4[(size_t)c * (NPIX / 4) + i];
        if (v.x > best.x) { best.x = v.x; bx = c; }    // strict > keeps FIRST max
        if (v.y > best.y) { best.y = v.y; by = c; }
        if (v.z > best.z) { best.z = v.z; bz = c; }
        if (v.w > best.w) { best.w = v.w; bw = c; }
    }
    lbl[i] = make_uchar4((unsigned char)bx, (unsigned char)by,
                         (unsigned char)bz, (unsigned char)bw);
}

// ---------------------------------------------------------------------------
// 2) per-(chunk, class) histogram: single-phase pred stream + L2-resident lbl.
//    LDS = 480 u32 = 1.9 KB (occupancy unconstrained). u32 packs (n|fg<<16),
//    chunk = 32768 pixels so both fit u16. Flush = u64 global atomicAdd per
//    bin straight into the FINAL histogram (322K atomics ~ 10 MB writes).
// ---------------------------------------------------------------------------
__global__ void __launch_bounds__(512)
k_hist(const fv4* __restrict__ pred4, const uchar4* __restrict__ lbl4,
       unsigned long long* __restrict__ hist) {
    __shared__ unsigned int sh[NBINS];
    const int chunk = blockIdx.x;
    const int c     = blockIdx.y;
    const int t     = threadIdx.x;

    for (int b = t; b < NBINS; b += 512) sh[b] = 0u;
    __syncthreads();

    const size_t pbase4 = ((size_t)c * NPIX + (size_t)chunk * CHUNK_PIX) / 4;
    const size_t lbase4 = ((size_t)chunk * CHUNK_PIX) / 4;
    constexpr int N4 = CHUNK_PIX / 4;                  // 8192 quads

    #pragma unroll 4
    for (int k = t; k < N4; k += 512) {
        fv4 p   = pred4[pbase4 + k];
        uchar4 l = lbl4[lbase4 + k];
        {
            unsigned int fg = (l.x == c) ? 1u : 0u;
            float e = fabsf((float)fg - p.x);
            int bin = (int)(e * BIN_SCALE); bin = bin < NBINS - 1 ? bin : NBINS - 1;
            atomicAdd(&sh[bin], 1u | (fg << 16));
        }
        {
            unsigned int fg = (l.y == c) ? 1u : 0u;
            float e = fabsf((float)fg - p.y);
            int bin = (int)(e * BIN_SCALE); bin = bin < NBINS - 1 ? bin : NBINS - 1;
            atomicAdd(&sh[bin], 1u | (fg << 16));
        }
        {
            unsigned int fg = (l.z == c) ? 1u : 0u;
            float e = fabsf((float)fg - p.z);
            int bin = (int)(e * BIN_SCALE); bin = bin < NBINS - 1 ? bin : NBINS - 1;
            atomicAdd(&sh[bin], 1u | (fg << 16));
        }
        {
            unsigned int fg = (l.w == c) ? 1u : 0u;
            float e = fabsf((float)fg - p.w);
            int bin = (int)(e * BIN_SCALE); bin = bin < NBINS - 1 ? bin : NBINS - 1;
            atomicAdd(&sh[bin], 1u | (fg << 16));
        }
    }
    __syncthreads();

    // flush: one u64 atomic per bin into the final per-class histogram
    for (int b = t; b < NBINS; b += 512) {
        unsigned int v = sh[b];
        if (v) {
            unsigned long long add =
                (unsigned long long)(v & 0xFFFFu) |
                ((unsigned long long)(v >> 16) << 32);
            atomicAdd(&hist[(size_t)c * NBINS + b], add);
        }
    }
}

// ---------------------------------------------------------------------------
// 3) per-class descending scan + Lovasz dot + mean: one block per class
//    (512 threads); thread t owns descending rank t (bin NBINS-1-t);
//    shuffle-scan, then one atomicAdd of loss_c/NCLS into out[0].
// ---------------------------------------------------------------------------
__global__ void __launch_bounds__(512)
k_scanfinal(const unsigned long long* __restrict__ hist, float* __restrict__ out) {
    const int c    = blockIdx.x;
    const int t    = threadIdx.x;
    const int lane = t & 63;
    const int wv   = t >> 6;                           // 8 waves

    const int bin = NBINS - 1 - t;                     // valid when t < NBINS
    unsigned int tn = 0, tf = 0;
    if (t < NBINS) {
        unsigned long long v = hist[(size_t)c * NBINS + bin];
        tn = (unsigned int)v;
        tf = (unsigned int)(v >> 32);
    }

    // wave-inclusive scan of (tn, tf)
    unsigned int in_ = tn, if_ = tf;
    #pragma unroll
    for (int off = 1; off < 64; off <<= 1) {
        unsigned int an = __shfl_up(in_, off, 64);
        unsigned int af = __shfl_up(if_, off, 64);
        if (lane >= off) { in_ += an; if_ += af; }
    }

    __shared__ unsigned int swn[8], swf[8];
    if (lane == 63) { swn[wv] = in_; swf[wv] = if_; }
    __syncthreads();

    if (wv == 0 && lane < 8) {                         // scan the 8 wave totals
        unsigned int a = swn[lane], b = swf[lane];
        #pragma unroll
        for (int off = 1; off < 8; off <<= 1) {
            unsigned int an = __shfl_up(a, off, 64);
            unsigned int af = __shfl_up(b, off, 64);
            if (lane >= off) { a += an; b += af; }
        }
        swn[lane] = a; swf[lane] = b;                  // inclusive wave prefixes
    }
    __syncthreads();

    const unsigned int G = swf[7];                     // total foreground count
    unsigned int i = in_ - tn + (wv ? swn[wv - 1] : 0u);   // exclusive prefix
    unsigned int F = if_ - tf + (wv ? swf[wv - 1] : 0u);

    double acc = 0.0;
    if (tn) {
        double jprev = (i > 0) ? (double)i / (double)(G + i - F) : 0.0;
        unsigned int i2 = i + tn, F2 = F + tf;
        double jhi = (double)i2 / (double)(G + i2 - F2);
        acc = ((bin + 0.5) * (double)(RANGE / NBINS)) * (jhi - jprev);
    }

    // block reduce, then one atomicAdd per class
    #pragma unroll
    for (int off = 32; off > 0; off >>= 1) acc += __shfl_down(acc, off, 64);
    __shared__ double sd[8];
    if (lane == 0) sd[wv] = acc;
    __syncthreads();
    if (t == 0) {
        double s = 0.0;
        #pragma unroll
        for (int k = 0; k < 8; ++k) s += sd[k];
        atomicAdd(out, (float)(s / NCLS));
    }
}

extern "C" void kernel_launch(void* const* d_in, const int* in_sizes, int n_in,
                              void* d_out, int out_size, void* d_ws, size_t ws_size,
                              hipStream_t stream) {
    const float* pred  = (const float*)d_in[0];
    const int*   label = (const int*)d_in[1];
    float* out = (float*)d_out;

    char* ws = (char*)d_ws;
    unsigned char* lbl = (unsigned char*)ws;                     // 1 MB
    size_t off = (size_t)NPIX;
    unsigned long long* hist = (unsigned long long*)(ws + off);  // 80.6 KB

    k_argmax<<<NPIX / 4 / 256, 256, 0, stream>>>((const iv4*)label, (uchar4*)lbl,
                                                 hist, out);
    dim3 hgrid(NCHUNK, NCLS);
    k_hist<<<hgrid, 512, 0, stream>>>((const fv4*)pred, (const uchar4*)lbl, hist);
    k_scanfinal<<<NCLS, 512, 0, stream>>>(hist, out);
}